// Round 2
// baseline (955.346 us; speedup 1.0000x reference)
//
#include <hip/hip_runtime.h>

// ST-BIF IF neuron, multistep. x_seq: (T=16, B=64, N=196, D=768) fp32.
// Scan over T carries per-element state (q, acc); parallel over the
// 9,633,792 spatial elements. One thread owns 4 consecutive elements
// (native float4 vector), keeps state in registers, loops T=16 in-register.
//
// Memory-bound: 616.6 MB in + 616.6 MB out, zero reuse -> nontemporal
// vector load/store, coalesced (lane i -> x[t*S + 4i..4i+3]).
//
// Numerics: acc is exactly integer (0 +/- 1 steps) so round() is a no-op;
// qt = 0.5 exactly so x*(1/qt) == x/qt bitwise; q-1>=0 <=> q>=1 (Sterbenz).

typedef float f32x4 __attribute__((ext_vector_type(4)));  // native vector:
// __builtin_nontemporal_* requires scalar/pointer/clang-vector types, not
// the HIP_vector_type struct that hip float4 is.

static constexpr int T_STEPS    = 16;
static constexpr int STEP_ELEMS = 64 * 196 * 768;   // 9,633,792 per step
static constexpr int NV         = STEP_ELEMS / 4;   // 2,408,448 vec4 per step
static constexpr float POS_MAX  = 7.0f;             // LEVEL/2 - 1
static constexpr float NEG_MIN  = -8.0f;            // -(LEVEL/2)

__device__ __forceinline__ float if_step(float xin, float inv, float qt,
                                         float& q, float& a) {
  q += xin * inv;                       // q = q + x/q_threshold (exact for qt=0.5)
  // acc = round(acc) is a no-op: acc is exactly integer.
  const bool spike = (q >= 1.0f) && (a < POS_MAX);
  const bool neg   = (q <  0.0f) && (a > NEG_MIN);
  const float cur  = spike ? 1.0f : (neg ? -1.0f : 0.0f);
  a += cur;
  q -= cur;
  return cur * qt;
}

__global__ __launch_bounds__(256) void ifneuron_kernel(
    const f32x4* __restrict__ x, const float* __restrict__ qthr_p,
    f32x4* __restrict__ out) {
  const int i = blockIdx.x * 256 + threadIdx.x;
  if (i >= NV) return;

  const float qt  = qthr_p[0];
  const float inv = 1.0f / qt;

  float q0 = 0.5f, q1 = 0.5f, q2 = 0.5f, q3 = 0.5f;
  float a0 = 0.0f, a1 = 0.0f, a2 = 0.0f, a3 = 0.0f;

#pragma unroll
  for (int t = 0; t < T_STEPS; ++t) {
    const size_t off = (size_t)t * NV + (size_t)i;
    const f32x4 xin = __builtin_nontemporal_load(&x[off]);
    f32x4 o;
    o.x = if_step(xin.x, inv, qt, q0, a0);
    o.y = if_step(xin.y, inv, qt, q1, a1);
    o.z = if_step(xin.z, inv, qt, q2, a2);
    o.w = if_step(xin.w, inv, qt, q3, a3);
    __builtin_nontemporal_store(o, &out[off]);
  }
}

extern "C" void kernel_launch(void* const* d_in, const int* in_sizes, int n_in,
                              void* d_out, int out_size, void* d_ws, size_t ws_size,
                              hipStream_t stream) {
  const f32x4* x   = (const f32x4*)d_in[0];
  const float* qt  = (const float*)d_in[1];
  f32x4*       out = (f32x4*)d_out;

  const int blocks = (NV + 255) / 256;   // 9408 exactly
  ifneuron_kernel<<<dim3(blocks), dim3(256), 0, stream>>>(x, qt, out);
}